// Round 3
// baseline (493.055 us; speedup 1.0000x reference)
//
#include <hip/hip_runtime.h>
#include <math.h>

#define HIDDEN  2048
#define NEXP    256
#define TOPK    8
#define NGROUP  8
#define TKG     4
#define GSZ     32
#define TM      32                 // tokens per block
#define KC      32                 // k-chunk (two 16-elem SSE groups)
#define NCHUNK  (HIDDEN / KC)      // 64
#define LGSTR   (NEXP + 2)         // logits row stride in pool

// Bit-exact emulation of numpy c_einsum's f32 dot kernel
// (sum_of_products_contig_contig_outstride0_two, SSE baseline, vstep=4):
//   - 4 lane-chains (k mod 4), mul and add SEPARATELY rounded (no FMA)
//   - 16-elem groups ascending; within a group the four float4s are
//     accumulated in REVERSED order (v=3,2,1,0)
//   - final combine (A0+A1)+(A2+A3)  [SSE3 double-hadd]
__global__ __launch_bounds__(256, 2) void moe_gate_main(
    const float* __restrict__ X,      // [T, HIDDEN]
    const float* __restrict__ W,      // [NEXP, HIDDEN]
    float* __restrict__ out,          // [T*8 idx][T*8 w][1 loss]
    double* __restrict__ S_ws,        // [NEXP]
    int* __restrict__ cnt_ws,         // [NEXP]
    int T)
{
#pragma clang fp contract(off)
    __shared__ __align__(16) float xs[TM][KC];          // 4 KB
    __shared__ __align__(16) float pool[TM * LGSTR];    // 33 KB: W tile, then logits
    __shared__ float dmax[TM];
    __shared__ float den[TM];

    const int tid = threadIdx.x;
    const int tg  = tid >> 6;        // wave id -> token octet (wave-uniform)
    const int exq = tid & 63;        // expert base lane
    const int t0  = blockIdx.x * TM;
    const int swz = exq & 7;

    float4 acc[8][4];
#pragma unroll
    for (int i = 0; i < 8; ++i)
#pragma unroll
        for (int j = 0; j < 4; ++j) acc[i][j] = make_float4(0.f, 0.f, 0.f, 0.f);

    for (int c = 0; c < NCHUNK; ++c) {
        const int k0 = c * KC;
        __syncthreads();
        // stage X chunk [32][32]: one float4 per thread, coalesced, conflict-free
        {
            const int trow = tid >> 3, col4 = tid & 7;
            const float4 v = *(const float4*)(X + (size_t)(t0 + trow) * HIDDEN + k0 + 4 * col4);
            *(float4*)&xs[trow][4 * col4] = v;
        }
        // stage W chunk [256][32], XOR-swizzled 16B columns (bank-conflict-free reads)
#pragma unroll
        for (int it = 0; it < 8; ++it) {
            const int f4  = it * 256 + tid;
            const int row = f4 >> 3, col4 = f4 & 7;
            const float4 v = *(const float4*)(W + (size_t)row * HIDDEN + k0 + 4 * col4);
            *(float4*)&pool[row * KC + ((col4 ^ (row & 7)) * 4)] = v;
        }
        __syncthreads();
        // two 16-elem groups, vectors reversed within each group (SSE chain order)
#pragma unroll
        for (int blk = 0; blk < 2; ++blk) {
#pragma unroll
            for (int vv = 3; vv >= 0; --vv) {
                const int k4 = blk * 4 + vv;
                const int sc = (k4 ^ swz) * 4;
                float4 wv[4];
#pragma unroll
                for (int j = 0; j < 4; ++j)
                    wv[j] = *(const float4*)&pool[(exq + 64 * j) * KC + sc];
#pragma unroll
                for (int i = 0; i < 8; ++i) {
                    const float4 xv = *(const float4*)&xs[tg * 8 + i][4 * k4]; // broadcast
#pragma unroll
                    for (int j = 0; j < 4; ++j) {
                        acc[i][j].x = __fadd_rn(acc[i][j].x, __fmul_rn(xv.x, wv[j].x));
                        acc[i][j].y = __fadd_rn(acc[i][j].y, __fmul_rn(xv.y, wv[j].y));
                        acc[i][j].z = __fadd_rn(acc[i][j].z, __fmul_rn(xv.z, wv[j].z));
                        acc[i][j].w = __fadd_rn(acc[i][j].w, __fmul_rn(xv.w, wv[j].w));
                    }
                }
            }
        }
    }

    __syncthreads();   // W-tile dead; pool becomes logits
#pragma unroll
    for (int i = 0; i < 8; ++i)
#pragma unroll
        for (int j = 0; j < 4; ++j) {
            const float4 a = acc[i][j];
            // SSE3 hadd x2: (A0+A1)+(A2+A3)
            pool[(tg * 8 + i) * LGSTR + exq + 64 * j] =
                __fadd_rn(__fadd_rn(a.x, a.y), __fadd_rn(a.z, a.w));
        }
    __syncthreads();

    // ---- per-token selection: grouped top-4, global top-8, softmax weights ----
    if (tid < TM) {
        const int t = tid;
        float cv[NGROUP * TKG];
        int   ci[NGROUP * TKG];
        float gmax = -3.0e38f;

        for (int g = 0; g < NGROUP; ++g) {
            float v4[TKG] = { -3.0e38f, -3.0e38f, -3.0e38f, -3.0e38f };
            int   i4[TKG] = { 0, 0, 0, 0 };
            for (int jj = 0; jj < GSZ; ++jj) {
                const float v = pool[t * LGSTR + g * GSZ + jj];
                if (v > gmax) gmax = v;
                if (v > v4[TKG - 1]) {          // strict > : stable (lower idx first)
                    int q = TKG - 1;
                    while (q > 0 && v > v4[q - 1]) {
                        v4[q] = v4[q - 1]; i4[q] = i4[q - 1]; --q;
                    }
                    v4[q] = v; i4[q] = jj;
                }
            }
#pragma unroll
            for (int r = 0; r < TKG; ++r) { cv[g * TKG + r] = v4[r]; ci[g * TKG + r] = i4[r]; }
        }

        float v8[TOPK]; int p8[TOPK];
#pragma unroll
        for (int k = 0; k < TOPK; ++k) { v8[k] = -3.0e38f; p8[k] = 0; }
        for (int p = 0; p < NGROUP * TKG; ++p) {
            const float v = cv[p];
            if (v > v8[TOPK - 1]) {             // strict > : stable by candidate pos
                int q = TOPK - 1;
                while (q > 0 && v > v8[q - 1]) {
                    v8[q] = v8[q - 1]; p8[q] = p8[q - 1]; --q;
                }
                v8[q] = v; p8[q] = p;
            }
        }

        float w8[TOPK]; float ssum = 0.f;
#pragma unroll
        for (int k = 0; k < TOPK; ++k) {
            w8[k] = expf(v8[k] - v8[0]);
            ssum += w8[k];
        }

        const size_t row = (size_t)(t0 + t) * TOPK;
#pragma unroll
        for (int k = 0; k < TOPK; ++k) {
            const int pos = p8[k];
            const int ex  = (pos >> 2) * GSZ + ci[pos];
            out[row + k] = (float)ex;
            out[(size_t)T * TOPK + row + k] = w8[k] / ssum;
            atomicAdd(&cnt_ws[ex], 1);
        }

        float dsum = 0.f;
        for (int e2 = 0; e2 < NEXP; ++e2)
            dsum += expf(pool[t * LGSTR + e2] - gmax);
        dmax[t] = gmax;
        den[t]  = dsum;
    }
    __syncthreads();

    // ---- per-expert partial sum of probs over this block's tokens ----
    double part = 0.0;
#pragma unroll
    for (int t = 0; t < TM; ++t)
        part += (double)(expf(pool[t * LGSTR + tid] - dmax[t]) / den[t]);
    atomicAdd(&S_ws[tid], part);
}

// ---------------- tiny loss-finalize kernel ----------------
__global__ __launch_bounds__(256) void moe_gate_loss(
    const double* __restrict__ S_ws, const int* __restrict__ cnt_ws,
    float* __restrict__ out, int T)
{
    __shared__ double red[NEXP];
    const int e = threadIdx.x;
    const double S = S_ws[e];
    const double c = (double)cnt_ws[e];
    const double Td = (double)T;
    const double aux = (c / Td) * (S / Td);
    double z = log(S); z *= z;

    red[e] = aux; __syncthreads();
    for (int s = 128; s > 0; s >>= 1) { if (e < s) red[e] += red[e + s]; __syncthreads(); }
    const double auxsum = red[0];
    __syncthreads();
    red[e] = z; __syncthreads();
    for (int s = 128; s > 0; s >>= 1) { if (e < s) red[e] += red[e + s]; __syncthreads(); }
    if (e == 0)
        out[(size_t)T * TOPK * 2] = (float)(auxsum * 1.0e-3 + (red[0] / (double)NEXP) * 1.0e-4);
}

extern "C" void kernel_launch(void* const* d_in, const int* in_sizes, int n_in,
                              void* d_out, int out_size, void* d_ws, size_t ws_size,
                              hipStream_t stream)
{
    const float* X = (const float*)d_in[0];
    const float* W = (const float*)d_in[1];
    float* out = (float*)d_out;
    const int T = in_sizes[0] / HIDDEN;   // 16384

    double* S_ws   = (double*)d_ws;
    int*    cnt_ws = (int*)((char*)d_ws + NEXP * sizeof(double));

    hipMemsetAsync(d_ws, 0, NEXP * (sizeof(double) + sizeof(int)), stream);

    moe_gate_main<<<dim3(T / TM), dim3(256), 0, stream>>>(X, W, out, S_ws, cnt_ws, T);
    moe_gate_loss<<<dim3(1), dim3(256), 0, stream>>>(S_ws, cnt_ws, out, T);
}